// Round 5
// baseline (218.460 us; speedup 1.0000x reference)
//
#include <hip/hip_runtime.h>

#define NB 8192
#define NS 50
#define ND 128
#define NP 16
#define NU 50000
#define NRED 128   // stage-1 reduction blocks for shared-proto mean

typedef float f4v __attribute__((ext_vector_type(4)));

// ---------------- scatter map (no init needed: entries validated on read) ----
__global__ void k_scatter_map(const int* __restrict__ user_idx, int* __restrict__ map) {
    int b = blockIdx.x * blockDim.x + threadIdx.x;
    if (b < NB) map[user_idx[b]] = b;
}

// ---------------- fused main kernel ----------------
// one 256-thread block per user row u, with a stride permutation so heavy
// (mapped) rows are spread uniformly across the dispatch instead of
// front-loaded. map validation: entry b live iff 0<=b<NB and user_idx[b]==u
// (correct for any stale ws content).
__global__ __launch_bounds__(256) void k_big(
    const float* __restrict__ proto,
    const float* __restrict__ ic,
    const float* __restrict__ features,
    const float* __restrict__ mask,
    const int* __restrict__ map,
    const int* __restrict__ user_idx,
    float* __restrict__ out_proto,
    float* __restrict__ out_ic,
    float* __restrict__ upd)
{
    // bijective interleave: gcd(40009, 50000) = 1
    int u = (int)(((long long)blockIdx.x * 40009LL) % NU);
    int t = threadIdx.x;

    int b = map[u];
    bool mapped = (b >= 0) && (b < NB);
    if (mapped) mapped = (user_idx[b] == u);

    const f4v* proto4 = (const f4v*)proto;
    f4v* out4 = (f4v*)out_proto;
    size_t base = (size_t)u * (NP * ND / 4);   // 512 float4 per row

    if (!mapped) {
        // pure streaming copy row, bypass caches
        f4v v0 = __builtin_nontemporal_load(&proto4[base + t]);
        f4v v1 = __builtin_nontemporal_load(&proto4[base + t + 256]);
        __builtin_nontemporal_store(v0, &out4[base + t]);
        __builtin_nontemporal_store(v1, &out4[base + t + 256]);
        if (t == 0) out_ic[u] = ic[u];
        return;
    }

    // prefetch this row's prototypes; latency hides under the feature reduce
    f4v p0 = __builtin_nontemporal_load(&proto4[base + t]);
    f4v p1 = __builtin_nontemporal_load(&proto4[base + t + 256]);
    float icv = ic[u];

    __shared__ float smask[NS];
    __shared__ f4v   part[8][32];
    __shared__ f4v   updv[32];

    if (t < NS) smask[t] = mask[(size_t)b * NS + t];
    __syncthreads();

    // masked accumulation: thread t -> float4 column q = t&31, s-group g = t>>5
    int q = t & 31;
    int g = t >> 5;
    const f4v* f4 = (const f4v*)features + (size_t)b * (NS * ND / 4);
    f4v acc = {0.f, 0.f, 0.f, 0.f};
    for (int s = g; s < NS; s += 8) {
        float w = smask[s];
        f4v v = __builtin_nontemporal_load(&f4[s * 32 + q]);
        acc += v * w;
    }
    part[g][q] = acc;
    __syncthreads();

    if (t < 32) {
        float msum = 0.f;
#pragma unroll
        for (int s = 0; s < NS; ++s) msum += smask[s];

        f4v a = part[0][t];
#pragma unroll
        for (int g2 = 1; g2 < 8; ++g2) a += part[g2][t];

        a *= (1.0f / fmaxf(msum, 1e-6f));

        // L2 norm across 128 dims (32 lanes x 4)
        float d2 = a.x * a.x + a.y * a.y + a.z * a.z + a.w * a.w;
#pragma unroll
        for (int mm = 16; mm >= 1; mm >>= 1) d2 += __shfl_xor(d2, mm, 64);
        a *= (1.0f / fmaxf(sqrtf(d2), 1e-12f));

        updv[t] = a;
        ((f4v*)upd)[(size_t)b * 32 + t] = a;   // consumed by k_colsum
    }
    __syncthreads();

    float m = fminf(fmaxf(0.9f + icv * 0.001f, 0.9f), 0.99f);
    float om = 1.0f - m;
    if (t == 0) out_ic[u] = icv + 1.0f;

    f4v u0 = updv[t & 31];
    p0 = m * p0 + om * u0;
    p1 = m * p1 + om * u0;
    __builtin_nontemporal_store(p0, &out4[base + t]);
    __builtin_nontemporal_store(p1, &out4[base + t + 256]);
}

// ---------------- stage-1 column sum over B ----------------
__global__ void k_colsum(const float* __restrict__ upd, float* __restrict__ part) {
    int blk = blockIdx.x;
    int t = threadIdx.x;
    int d = t & 127;
    int h = t >> 7;

    const int rows = NB / NRED;          // 64
    int r0 = blk * rows;

    float s = 0.f;
    for (int r = r0 + h; r < r0 + rows; r += 2)
        s += upd[(size_t)r * ND + d];

    __shared__ float red[2][ND];
    red[h][d] = s;
    __syncthreads();
    if (h == 0)
        part[(size_t)blk * ND + d] = red[0][d] + red[1][d];
}

// ---------------- stage-2: mean, normalize, blend shared ----------------
__global__ void k_shared_final(const float* __restrict__ part,
                               const float* __restrict__ shared_in,
                               float* __restrict__ shared_out) {
    int d = threadIdx.x;   // 0..127

    float tot = 0.f;
#pragma unroll
    for (int j = 0; j < NRED; ++j) tot += part[(size_t)j * ND + d];
    float mean = tot / (float)NB;

    __shared__ float red[ND];
    red[d] = mean * mean;
    __syncthreads();
    for (int off = 64; off > 0; off >>= 1) {
        if (d < off) red[d] += red[d + off];
        __syncthreads();
    }
    float inv = 1.0f / fmaxf(sqrtf(red[0]), 1e-12f);
    float su = mean * inv;

#pragma unroll
    for (int p = 0; p < NP; ++p)
        shared_out[p * ND + d] = 0.9f * shared_in[p * ND + d] + 0.1f * su;
}

extern "C" void kernel_launch(void* const* d_in, const int* in_sizes, int n_in,
                              void* d_out, int out_size, void* d_ws, size_t ws_size,
                              hipStream_t stream) {
    const float* user_prototypes   = (const float*)d_in[0];  // [NU, NP, ND]
    const float* shared_prototypes = (const float*)d_in[1];  // [1, NP, ND]
    const float* interaction_count = (const float*)d_in[2];  // [NU]
    const float* features          = (const float*)d_in[3];  // [NB, NS, ND]
    const float* success_mask      = (const float*)d_in[4];  // [NB, NS]
    const int*   user_idx          = (const int*)d_in[5];    // [NB]

    float* out_proto  = (float*)d_out;                         // NU*NP*ND
    float* out_shared = out_proto + (size_t)NU * NP * ND;      // NP*ND
    float* out_ic     = out_shared + NP * ND;                  // NU

    // workspace layout (16B aligned chunks)
    int*   map  = (int*)d_ws;                                  // NU ints (200 KB)
    float* upd  = (float*)((char*)d_ws + 200704);              // NB*ND floats (4 MB)
    float* part = upd + (size_t)NB * ND;                       // NRED*ND floats (64 KB)

    k_scatter_map<<<(NB + 255) / 256, 256, 0, stream>>>(user_idx, map);

    k_big<<<NU, 256, 0, stream>>>(user_prototypes, interaction_count,
                                  features, success_mask, map, user_idx,
                                  out_proto, out_ic, upd);

    k_colsum<<<NRED, 256, 0, stream>>>(upd, part);
    k_shared_final<<<1, ND, 0, stream>>>(part, shared_prototypes, out_shared);
}

// Round 6
// 190.154 us; speedup vs baseline: 1.1489x; 1.1489x over previous
//
#include <hip/hip_runtime.h>

#define NB 8192
#define NS 50
#define ND 128
#define NP 16
#define NU 50000
#define NRED 128   // stage-1 reduction blocks for shared-proto mean

typedef float f4v __attribute__((ext_vector_type(4)));

// ---------------- scatter map (no init needed: entries validated on read) ----
__global__ void k_scatter_map(const int* __restrict__ user_idx, int* __restrict__ map) {
    int b = blockIdx.x * blockDim.x + threadIdx.x;
    if (b < NB) map[user_idx[b]] = b;
}

// ---------------- fused main kernel ----------------
// one 256-thread block per user row u, LINEAR block order (R5's permuted
// order broke the sequential HBM stream and cost 13%).
// map validation: entry b live iff 0<=b<NB and user_idx[b]==u
// (correct for any stale ws content).
__global__ __launch_bounds__(256) void k_big(
    const float* __restrict__ proto,
    const float* __restrict__ ic,
    const float* __restrict__ features,
    const float* __restrict__ mask,
    const int* __restrict__ map,
    const int* __restrict__ user_idx,
    float* __restrict__ out_proto,
    float* __restrict__ out_ic,
    float* __restrict__ upd)
{
    int u = blockIdx.x;
    int t = threadIdx.x;

    int b = map[u];
    bool mapped = (b >= 0) && (b < NB);
    if (mapped) mapped = (user_idx[b] == u);

    const f4v* proto4 = (const f4v*)proto;
    f4v* out4 = (f4v*)out_proto;
    size_t base = (size_t)u * (NP * ND / 4);   // 512 float4 per row

    if (!mapped) {
        // pure streaming copy row, bypass caches
        f4v v0 = __builtin_nontemporal_load(&proto4[base + t]);
        f4v v1 = __builtin_nontemporal_load(&proto4[base + t + 256]);
        __builtin_nontemporal_store(v0, &out4[base + t]);
        __builtin_nontemporal_store(v1, &out4[base + t + 256]);
        if (t == 0) out_ic[u] = ic[u];
        return;
    }

    // prefetch this row's prototypes; latency hides under the feature reduce
    f4v p0 = __builtin_nontemporal_load(&proto4[base + t]);
    f4v p1 = __builtin_nontemporal_load(&proto4[base + t + 256]);
    float icv = ic[u];

    __shared__ float smask[NS];
    __shared__ f4v   part[8][32];
    __shared__ f4v   updv[32];

    if (t < NS) smask[t] = mask[(size_t)b * NS + t];
    __syncthreads();

    // masked accumulation: thread t -> float4 column q = t&31, s-group g = t>>5
    int q = t & 31;
    int g = t >> 5;
    const f4v* f4 = (const f4v*)features + (size_t)b * (NS * ND / 4);
    f4v acc = {0.f, 0.f, 0.f, 0.f};
    for (int s = g; s < NS; s += 8) {
        float w = smask[s];
        f4v v = __builtin_nontemporal_load(&f4[s * 32 + q]);
        acc += v * w;
    }
    part[g][q] = acc;
    __syncthreads();

    if (t < 32) {
        float msum = 0.f;
#pragma unroll
        for (int s = 0; s < NS; ++s) msum += smask[s];

        f4v a = part[0][t];
#pragma unroll
        for (int g2 = 1; g2 < 8; ++g2) a += part[g2][t];

        a *= (1.0f / fmaxf(msum, 1e-6f));

        // L2 norm across 128 dims (32 lanes x 4)
        float d2 = a.x * a.x + a.y * a.y + a.z * a.z + a.w * a.w;
#pragma unroll
        for (int mm = 16; mm >= 1; mm >>= 1) d2 += __shfl_xor(d2, mm, 64);
        a *= (1.0f / fmaxf(sqrtf(d2), 1e-12f));

        updv[t] = a;
        ((f4v*)upd)[(size_t)b * 32 + t] = a;   // consumed by k_colsum
    }
    __syncthreads();

    float m = fminf(fmaxf(0.9f + icv * 0.001f, 0.9f), 0.99f);
    float om = 1.0f - m;
    if (t == 0) out_ic[u] = icv + 1.0f;

    f4v u0 = updv[t & 31];
    p0 = m * p0 + om * u0;
    p1 = m * p1 + om * u0;
    __builtin_nontemporal_store(p0, &out4[base + t]);
    __builtin_nontemporal_store(p1, &out4[base + t + 256]);
}

// ---------------- stage-1 column sum over B ----------------
__global__ void k_colsum(const float* __restrict__ upd, float* __restrict__ part) {
    int blk = blockIdx.x;
    int t = threadIdx.x;
    int d = t & 127;
    int h = t >> 7;

    const int rows = NB / NRED;          // 64
    int r0 = blk * rows;

    float s = 0.f;
    for (int r = r0 + h; r < r0 + rows; r += 2)
        s += upd[(size_t)r * ND + d];

    __shared__ float red[2][ND];
    red[h][d] = s;
    __syncthreads();
    if (h == 0)
        part[(size_t)blk * ND + d] = red[0][d] + red[1][d];
}

// ---------------- stage-2: mean, normalize, blend shared ----------------
__global__ void k_shared_final(const float* __restrict__ part,
                               const float* __restrict__ shared_in,
                               float* __restrict__ shared_out) {
    int d = threadIdx.x;   // 0..127

    float tot = 0.f;
#pragma unroll
    for (int j = 0; j < NRED; ++j) tot += part[(size_t)j * ND + d];
    float mean = tot / (float)NB;

    __shared__ float red[ND];
    red[d] = mean * mean;
    __syncthreads();
    for (int off = 64; off > 0; off >>= 1) {
        if (d < off) red[d] += red[d + off];
        __syncthreads();
    }
    float inv = 1.0f / fmaxf(sqrtf(red[0]), 1e-12f);
    float su = mean * inv;

#pragma unroll
    for (int p = 0; p < NP; ++p)
        shared_out[p * ND + d] = 0.9f * shared_in[p * ND + d] + 0.1f * su;
}

extern "C" void kernel_launch(void* const* d_in, const int* in_sizes, int n_in,
                              void* d_out, int out_size, void* d_ws, size_t ws_size,
                              hipStream_t stream) {
    const float* user_prototypes   = (const float*)d_in[0];  // [NU, NP, ND]
    const float* shared_prototypes = (const float*)d_in[1];  // [1, NP, ND]
    const float* interaction_count = (const float*)d_in[2];  // [NU]
    const float* features          = (const float*)d_in[3];  // [NB, NS, ND]
    const float* success_mask      = (const float*)d_in[4];  // [NB, NS]
    const int*   user_idx          = (const int*)d_in[5];    // [NB]

    float* out_proto  = (float*)d_out;                         // NU*NP*ND
    float* out_shared = out_proto + (size_t)NU * NP * ND;      // NP*ND
    float* out_ic     = out_shared + NP * ND;                  // NU

    // workspace layout (16B aligned chunks)
    int*   map  = (int*)d_ws;                                  // NU ints (200 KB)
    float* upd  = (float*)((char*)d_ws + 200704);              // NB*ND floats (4 MB)
    float* part = upd + (size_t)NB * ND;                       // NRED*ND floats (64 KB)

    k_scatter_map<<<(NB + 255) / 256, 256, 0, stream>>>(user_idx, map);

    k_big<<<NU, 256, 0, stream>>>(user_prototypes, interaction_count,
                                  features, success_mask, map, user_idx,
                                  out_proto, out_ic, upd);

    k_colsum<<<NRED, 256, 0, stream>>>(upd, part);
    k_shared_final<<<1, ND, 0, stream>>>(part, shared_prototypes, out_shared);
}

// Round 7
// 181.421 us; speedup vs baseline: 1.2042x; 1.0481x over previous
//
#include <hip/hip_runtime.h>

#define NB 8192
#define NS 50
#define ND 128
#define NP 16
#define NU 50000
#define NRED 128   // stage-1 reduction blocks for shared-proto mean

typedef float f4v __attribute__((ext_vector_type(4)));

// ---------------- scatter map (no init needed: entries validated on read) ----
__global__ void k_scatter_map(const int* __restrict__ user_idx, int* __restrict__ map) {
    int b = blockIdx.x * blockDim.x + threadIdx.x;
    if (b < NB) map[user_idx[b]] = b;
}

// ---------------- phase 1: per-batch update vector ----------------
// one 256-thread block per batch element b; pure feature-read reduce.
__global__ __launch_bounds__(256) void k_upd(
    const float* __restrict__ features,
    const float* __restrict__ mask,
    float* __restrict__ upd)
{
    int b = blockIdx.x;
    int t = threadIdx.x;

    __shared__ float smask[NS];
    __shared__ f4v   part[8][32];

    if (t < NS) smask[t] = mask[(size_t)b * NS + t];
    __syncthreads();

    // thread t -> float4 column q = t&31, s-group g = t>>5
    int q = t & 31;
    int g = t >> 5;
    const f4v* f4 = (const f4v*)features + (size_t)b * (NS * ND / 4);
    f4v acc = {0.f, 0.f, 0.f, 0.f};
    for (int s = g; s < NS; s += 8) {
        float w = smask[s];
        f4v v = __builtin_nontemporal_load(&f4[s * 32 + q]);
        acc += v * w;
    }
    part[g][q] = acc;
    __syncthreads();

    if (t < 32) {
        float msum = 0.f;
#pragma unroll
        for (int s = 0; s < NS; ++s) msum += smask[s];

        f4v a = part[0][t];
#pragma unroll
        for (int g2 = 1; g2 < 8; ++g2) a += part[g2][t];

        a *= (1.0f / fmaxf(msum, 1e-6f));

        // L2 norm across 128 dims (32 lanes x 4)
        float d2 = a.x * a.x + a.y * a.y + a.z * a.z + a.w * a.w;
#pragma unroll
        for (int mm = 16; mm >= 1; mm >>= 1) d2 += __shfl_xor(d2, mm, 64);
        a *= (1.0f / fmaxf(sqrtf(d2), 1e-12f));

        ((f4v*)upd)[(size_t)b * 32 + t] = a;
    }
}

// ---------------- phase 2: uniform streaming copy/blend ----------------
// one 256-thread block per user row; no LDS, no barriers, branch-uniform
// per block. upd row comes from L2/L3 (4 MB, just written).
__global__ __launch_bounds__(256) void k_blend(
    const float* __restrict__ proto,
    const float* __restrict__ ic,
    const int* __restrict__ map,
    const int* __restrict__ user_idx,
    const float* __restrict__ upd,
    float* __restrict__ out_proto,
    float* __restrict__ out_ic)
{
    int u = blockIdx.x;
    int t = threadIdx.x;

    int b = map[u];
    bool mapped = (b >= 0) && (b < NB);
    if (mapped) mapped = (user_idx[b] == u);

    const f4v* proto4 = (const f4v*)proto;
    f4v* out4 = (f4v*)out_proto;
    size_t base = (size_t)u * (NP * ND / 4);   // 512 float4 per row

    f4v v0 = __builtin_nontemporal_load(&proto4[base + t]);
    f4v v1 = __builtin_nontemporal_load(&proto4[base + t + 256]);

    if (mapped) {
        float icv = ic[u];
        float m = fminf(fmaxf(0.9f + icv * 0.001f, 0.9f), 0.99f);
        float om = 1.0f - m;
        f4v uu = ((const f4v*)upd)[(size_t)b * 32 + (t & 31)];
        v0 = m * v0 + om * uu;
        v1 = m * v1 + om * uu;
        if (t == 0) out_ic[u] = icv + 1.0f;
    } else {
        if (t == 0) out_ic[u] = ic[u];
    }

    __builtin_nontemporal_store(v0, &out4[base + t]);
    __builtin_nontemporal_store(v1, &out4[base + t + 256]);
}

// ---------------- stage-1 column sum over B ----------------
__global__ void k_colsum(const float* __restrict__ upd, float* __restrict__ part) {
    int blk = blockIdx.x;
    int t = threadIdx.x;
    int d = t & 127;
    int h = t >> 7;

    const int rows = NB / NRED;          // 64
    int r0 = blk * rows;

    float s = 0.f;
    for (int r = r0 + h; r < r0 + rows; r += 2)
        s += upd[(size_t)r * ND + d];

    __shared__ float red[2][ND];
    red[h][d] = s;
    __syncthreads();
    if (h == 0)
        part[(size_t)blk * ND + d] = red[0][d] + red[1][d];
}

// ---------------- stage-2: mean, normalize, blend shared ----------------
__global__ void k_shared_final(const float* __restrict__ part,
                               const float* __restrict__ shared_in,
                               float* __restrict__ shared_out) {
    int d = threadIdx.x;   // 0..127

    float tot = 0.f;
#pragma unroll
    for (int j = 0; j < NRED; ++j) tot += part[(size_t)j * ND + d];
    float mean = tot / (float)NB;

    __shared__ float red[ND];
    red[d] = mean * mean;
    __syncthreads();
    for (int off = 64; off > 0; off >>= 1) {
        if (d < off) red[d] += red[d + off];
        __syncthreads();
    }
    float inv = 1.0f / fmaxf(sqrtf(red[0]), 1e-12f);
    float su = mean * inv;

#pragma unroll
    for (int p = 0; p < NP; ++p)
        shared_out[p * ND + d] = 0.9f * shared_in[p * ND + d] + 0.1f * su;
}

extern "C" void kernel_launch(void* const* d_in, const int* in_sizes, int n_in,
                              void* d_out, int out_size, void* d_ws, size_t ws_size,
                              hipStream_t stream) {
    const float* user_prototypes   = (const float*)d_in[0];  // [NU, NP, ND]
    const float* shared_prototypes = (const float*)d_in[1];  // [1, NP, ND]
    const float* interaction_count = (const float*)d_in[2];  // [NU]
    const float* features          = (const float*)d_in[3];  // [NB, NS, ND]
    const float* success_mask      = (const float*)d_in[4];  // [NB, NS]
    const int*   user_idx          = (const int*)d_in[5];    // [NB]

    float* out_proto  = (float*)d_out;                         // NU*NP*ND
    float* out_shared = out_proto + (size_t)NU * NP * ND;      // NP*ND
    float* out_ic     = out_shared + NP * ND;                  // NU

    // workspace layout (16B aligned chunks)
    int*   map  = (int*)d_ws;                                  // NU ints (200 KB)
    float* upd  = (float*)((char*)d_ws + 200704);              // NB*ND floats (4 MB)
    float* part = upd + (size_t)NB * ND;                       // NRED*ND floats (64 KB)

    k_upd<<<NB, 256, 0, stream>>>(features, success_mask, upd);

    k_scatter_map<<<(NB + 255) / 256, 256, 0, stream>>>(user_idx, map);

    k_blend<<<NU, 256, 0, stream>>>(user_prototypes, interaction_count,
                                    map, user_idx, upd, out_proto, out_ic);

    k_colsum<<<NRED, 256, 0, stream>>>(upd, part);
    k_shared_final<<<1, ND, 0, stream>>>(part, shared_prototypes, out_shared);
}